// Round 17
// baseline (106.968 us; speedup 1.0000x reference)
//
#include <hip/hip_runtime.h>
#include <hip/hip_bf16.h>
#include <string.h>

#define SEQ 4096
#define DIM 512
#define NH  8
#define HD  64
#define SEQP (SEQ + 128)   // padded V row stride
#define NT  (SEQ/64)       // 64-key tiles
#define KSPLIT 4
#define KCHUNK (SEQ/KSPLIT)        // 1024 keys per split (pass B)
#define KTILES (KCHUNK/64)         // 16 tiles per split
#define PMSPLIT 8
#define KCHUNK_A (SEQ/PMSPLIT)     // 512 keys per split (pass A)
#define KTILES_A (KCHUNK_A/64)     // 8 tiles

typedef __attribute__((ext_vector_type(4))) float  f32x4;
typedef __attribute__((ext_vector_type(8))) short  bf16x8;
typedef __attribute__((ext_vector_type(4))) short  s16x4;
typedef __attribute__((ext_vector_type(2))) unsigned int u32x2;

// f32 -> bf16 via hardware convert (RNE on gfx950)
__device__ __forceinline__ unsigned short f2bfh(float f){
    union { __hip_bfloat16 h; unsigned short u; } cv;
    cv.h = __float2bfloat16(f);
    return cv.u;
}

__device__ __forceinline__ bf16x8 cvt8(f32x4 lo, f32x4 hi){
    bf16x8 r;
    r[0]=(short)f2bfh(lo[0]); r[1]=(short)f2bfh(lo[1]);
    r[2]=(short)f2bfh(lo[2]); r[3]=(short)f2bfh(lo[3]);
    r[4]=(short)f2bfh(hi[0]); r[5]=(short)f2bfh(hi[1]);
    r[6]=(short)f2bfh(hi[2]); r[7]=(short)f2bfh(hi[3]);
    return r;
}

__device__ __forceinline__ bf16x8 load8f(const float* p){
    f32x4 lo = *(const f32x4*)p;
    f32x4 hi = *(const f32x4*)(p+4);
    return cvt8(lo, hi);
}

// LDS-only fence: orders this wave's LDS ops; not a VALU/MFMA schedule wall.
#define FENCE_LDS() asm volatile("s_waitcnt lgkmcnt(0)" ::: "memory")

// ---------------------------------------------------------------------------
// Kernel 1: fused Q/K/V projections, cooperative LDS staging, f32 inputs
// converted to bf16 in the staging registers (cvt5 fused away; bit-identical).
// ---------------------------------------------------------------------------
__global__ __launch_bounds__(256, 4) void proj_qkv_b_kernel(
    const float* __restrict__ x,
    const float* __restrict__ Wq, const float* __restrict__ bq,
    const float* __restrict__ Wk, const float* __restrict__ bk,
    const float* __restrict__ Wv, const float* __restrict__ bv,
    unsigned short* __restrict__ Qb, unsigned short* __restrict__ Kh,
    unsigned short* __restrict__ Vtp)
{
    __shared__ __align__(16) unsigned short xs[128*64];   // 16KB
    __shared__ __align__(16) unsigned short wsh[64*64];   // 8KB

    const int z = blockIdx.z;
    const float* W  = (z==0) ? Wq : ((z==1) ? Wk : Wv);
    const float* bb = (z==0) ? bq : ((z==1) ? bk : bv);
    const int tid = threadIdx.x;
    const int wv  = tid >> 6;
    const int l   = tid & 63;
    const int g   = l >> 4;
    const int l15 = l & 15;
    const int l7  = l15 & 7;
    const int r0b = blockIdx.x * 128;
    const int c0  = blockIdx.y * 64;
    const int hy  = blockIdx.y;

    const int sc  = tid & 7;
    const int sr  = tid >> 3;                 // 0..31
    const int scs = (sc ^ (sr & 7)) * 8;      // swizzled granule offset

    f32x4 acc[2][4];
    #pragma unroll
    for(int s=0;s<2;s++)
        #pragma unroll
        for(int d=0;d<4;d++) acc[s][d] = (f32x4){0.f,0.f,0.f,0.f};

    bf16x8 xf[4], wf[2];
    #pragma unroll
    for(int j=0;j<4;j++)
        xf[j] = load8f(x + (size_t)(r0b + sr + 32*j)*DIM + sc*8);
    #pragma unroll
    for(int j=0;j<2;j++)
        wf[j] = load8f(W + (size_t)(c0 + sr + 32*j)*DIM + sc*8);

    for(int t=0;t<8;t++){
        #pragma unroll
        for(int j=0;j<4;j++)
            *(bf16x8*)&xs[(sr + 32*j)*64 + scs] = xf[j];
        #pragma unroll
        for(int j=0;j<2;j++)
            *(bf16x8*)&wsh[(sr + 32*j)*64 + scs] = wf[j];
        __syncthreads();
        if(t+1 < 8){
            const int kt = (t+1)*64;
            #pragma unroll
            for(int j=0;j<4;j++)
                xf[j] = load8f(x + (size_t)(r0b + sr + 32*j)*DIM + kt + sc*8);
            #pragma unroll
            for(int j=0;j<2;j++)
                wf[j] = load8f(W + (size_t)(c0 + sr + 32*j)*DIM + kt + sc*8);
        }
        #pragma unroll
        for(int kh=0;kh<2;kh++){
            bf16x8 a[2];
            #pragma unroll
            for(int s=0;s<2;s++){
                const int row = wv*32 + s*16 + l15;
                a[s] = *(const bf16x8*)&xs[row*64 + (((kh*4+g) ^ l7)*8)];
            }
            #pragma unroll
            for(int d=0;d<4;d++){
                const int row = d*16 + l15;
                bf16x8 b = *(const bf16x8*)&wsh[row*64 + (((kh*4+g) ^ l7)*8)];
                #pragma unroll
                for(int s=0;s<2;s++)
                    acc[s][d] = __builtin_amdgcn_mfma_f32_16x16x32_bf16(a[s], b, acc[s][d], 0,0,0);
            }
        }
        __syncthreads();
    }

    const int r0 = r0b + wv*32;
    #pragma unroll
    for(int d=0;d<4;d++){
        float bias = bb[c0 + d*16 + l15];
        #pragma unroll
        for(int s=0;s<2;s++){
            if(z == 2){
                s16x4 pk;
                #pragma unroll
                for(int r=0;r<4;r++) pk[r] = (short)f2bfh(acc[s][d][r] + bias);
                *(s16x4*)(Vtp + ((size_t)hy*HD + d*16+l15)*SEQP + r0 + s*16 + g*4) = pk;
            } else if(z == 1){
                #pragma unroll
                for(int r=0;r<4;r++)
                    Kh[((size_t)hy*SEQ + r0+s*16+g*4+r)*HD + d*16 + l15] =
                        f2bfh(acc[s][d][r] + bias);
            } else {
                #pragma unroll
                for(int r=0;r<4;r++)
                    Qb[(size_t)(r0+s*16+g*4+r)*DIM + c0 + d*16 + l15] =
                        f2bfh(acc[s][d][r] + bias);
            }
        }
    }
}

// ---------------------------------------------------------------------------
// Kernel 1 (fallback): unstaged, f32 weights with in-loop cvt
// ---------------------------------------------------------------------------
__global__ __launch_bounds__(256) void proj_qkv_kernel(
    const float* __restrict__ x,
    const float* __restrict__ Wq, const float* __restrict__ bq,
    const float* __restrict__ Wk, const float* __restrict__ bk,
    const float* __restrict__ Wv, const float* __restrict__ bv,
    unsigned short* __restrict__ Qb, unsigned short* __restrict__ Kh,
    unsigned short* __restrict__ Vtp)
{
    const int z = blockIdx.z;
    const float* W  = (z==0) ? Wq : ((z==1) ? Wk : Wv);
    const float* bb = (z==0) ? bq : ((z==1) ? bk : bv);
    const int wv  = threadIdx.x >> 6;
    const int l   = threadIdx.x & 63;
    const int g   = l >> 4;
    const int l15 = l & 15;
    const int r0  = blockIdx.x * 128 + wv * 32;
    const int c0  = blockIdx.y * 64;
    const int hy  = blockIdx.y;

    f32x4 acc[2][4];
    #pragma unroll
    for(int s=0;s<2;s++)
        #pragma unroll
        for(int d=0;d<4;d++) acc[s][d] = (f32x4){0.f,0.f,0.f,0.f};

    for(int kt=0; kt<DIM; kt+=32){
        bf16x8 a[2];
        #pragma unroll
        for(int s=0;s<2;s++)
            a[s] = load8f(x + (size_t)(r0+s*16+l15)*DIM + kt + g*8);
        #pragma unroll
        for(int d=0;d<4;d++){
            bf16x8 b = load8f(W + (size_t)(c0+d*16+l15)*DIM + kt + g*8);
            #pragma unroll
            for(int s=0;s<2;s++)
                acc[s][d] = __builtin_amdgcn_mfma_f32_16x16x32_bf16(a[s], b, acc[s][d], 0,0,0);
        }
    }

    #pragma unroll
    for(int d=0;d<4;d++){
        float bias = bb[c0 + d*16 + l15];
        #pragma unroll
        for(int s=0;s<2;s++){
            if(z == 2){
                s16x4 pk;
                #pragma unroll
                for(int r=0;r<4;r++) pk[r] = (short)f2bfh(acc[s][d][r] + bias);
                *(s16x4*)(Vtp + ((size_t)hy*HD + d*16+l15)*SEQP + r0 + s*16 + g*4) = pk;
            } else if(z == 1){
                #pragma unroll
                for(int r=0;r<4;r++)
                    Kh[((size_t)hy*SEQ + r0+s*16+g*4+r)*HD + d*16 + l15] =
                        f2bfh(acc[s][d][r] + bias);
            } else {
                #pragma unroll
                for(int r=0;r<4;r++)
                    Qb[(size_t)(r0+s*16+g*4+r)*DIM + c0 + d*16 + l15] =
                        f2bfh(acc[s][d][r] + bias);
            }
        }
    }
}

// ---------------------------------------------------------------------------
// Kernel 2a: pass A (row max), 8-way key-split, swapped QK^T, 32-row waves,
// 8 waves/block (256 q-rows), double-buffered K, ONE barrier per tile.
// ---------------------------------------------------------------------------
__global__ __launch_bounds__(512, 4) void attn_max_kernel(
    const unsigned short* __restrict__ Qb,
    const unsigned short* __restrict__ Kh,
    float* __restrict__ Pm)
{
    __shared__ __align__(16) unsigned short kb[2][64*64];   // 16KB

    const int tid = threadIdx.x;
    const int wv  = tid >> 6;
    const int l   = tid & 63;
    const int g   = l >> 4;
    const int l15 = l & 15;
    const int l7  = l15 & 7;
    const int h   = blockIdx.x & 7;
    const int kz  = (blockIdx.x >> 3) & 7;
    const int Rw  = (blockIdx.x >> 6) * 256 + wv * 32;
    const int kbase = kz * KCHUNK_A;

    const unsigned short* Khh = Kh + (size_t)h*SEQ*HD;
    const int sr  = tid >> 3, sc = tid & 7;   // sr 0..63
    const int scs = (sc ^ (sr & 7)) * 8;
    const int lA  = sr*64 + scs;

    bf16x8 aq[2][2];
    #pragma unroll
    for(int s=0;s<2;s++)
        #pragma unroll
        for(int kh=0;kh<2;kh++)
            aq[s][kh] = *(const bf16x8*)(Qb + (size_t)(Rw+s*16+l15)*DIM + h*HD + kh*32 + g*8);

    float mx[2];
    mx[0] = mx[1] = -3.0e38f;

    bf16x8 krA = *(const bf16x8*)(Khh + (size_t)(kbase+sr)*HD + sc*8);
    *(bf16x8*)&kb[0][lA] = krA;
    __syncthreads();

    for(int t=0;t<KTILES_A;t++){
        const int cur = t & 1;
        if(t+1 < KTILES_A)
            krA = *(const bf16x8*)(Khh + (size_t)(kbase+(t+1)*64+sr)*HD + sc*8);
        #pragma unroll
        for(int ks=0;ks<4;ks++){
            const int krow = ks*16 + l15;
            bf16x8 b0 = *(const bf16x8*)&kb[cur][krow*64 + ((g     ^ l7)*8)];
            bf16x8 b1 = *(const bf16x8*)&kb[cur][krow*64 + (((4+g) ^ l7)*8)];
            __builtin_amdgcn_s_setprio(1);
            #pragma unroll
            for(int s=0;s<2;s++){
                f32x4 acc = (f32x4){0.f,0.f,0.f,0.f};
                acc = __builtin_amdgcn_mfma_f32_16x16x32_bf16(b0, aq[s][0], acc, 0,0,0);
                acc = __builtin_amdgcn_mfma_f32_16x16x32_bf16(b1, aq[s][1], acc, 0,0,0);
                #pragma unroll
                for(int r=0;r<4;r++) mx[s] = fmaxf(mx[s], acc[r]);
            }
            __builtin_amdgcn_s_setprio(0);
        }
        if(t+1 < KTILES_A)
            *(bf16x8*)&kb[cur^1][lA] = krA;
        __syncthreads();
    }
    #pragma unroll
    for(int s=0;s<2;s++){
        mx[s] = fmaxf(mx[s], __shfl_xor(mx[s], 16, 64));
        mx[s] = fmaxf(mx[s], __shfl_xor(mx[s], 32, 64));
    }

    if(l < 16){
        Pm[(size_t)(h*PMSPLIT + kz)*SEQ + Rw + l15]      = mx[0];
        Pm[(size_t)(h*PMSPLIT + kz)*SEQ + Rw + 16 + l15] = mx[1];
    }
}

// ---------------------------------------------------------------------------
// Kernel 2b: pass B (fexp + PV), 4-way key-split, swapped QK^T, 32-row waves,
// 8 waves/block, double-buffered K/V, ONE barrier per tile.
// setprio around BOTH QK^T and PV MFMA clusters (best configuration).
// ---------------------------------------------------------------------------
#define PSTRIDE 68

__global__ __launch_bounds__(512, 4) void attn_pv_kernel(
    const unsigned short* __restrict__ Qb,
    const unsigned short* __restrict__ Kh,
    const unsigned short* __restrict__ Vtp,
    const float* __restrict__ Pm,
    float* __restrict__ numf,
    float* __restrict__ denf,
    float k1f)   // GIST_A * scaling
{
    __shared__ __align__(16) unsigned short kb[2][64*64];      // 16KB
    __shared__ __align__(16) unsigned short vb[2][64*64];      // 16KB
    __shared__ __align__(16) unsigned short pb[8][32*PSTRIDE]; // 34.8KB

    const int tid = threadIdx.x;
    const int wv  = tid >> 6;
    const int l   = tid & 63;
    const int g   = l >> 4;
    const int l15 = l & 15;
    const int l7  = l15 & 7;
    const int h   = blockIdx.x & 7;
    const int kz  = (blockIdx.x >> 3) & 3;
    const int Rw  = (blockIdx.x >> 5) * 256 + wv * 32;
    const int kbase = kz * KCHUNK;

    const unsigned short* Khh = Kh  + (size_t)h*SEQ*HD;
    const unsigned short* Vh  = Vtp + (size_t)h*HD*SEQP;

    const int sr  = tid >> 3, sc = tid & 7;   // sr 0..63
    const int scs = (sc ^ (sr & 7)) * 8;
    const int lA  = sr*64 + scs;

    bf16x8 aq[2][2];
    #pragma unroll
    for(int s=0;s<2;s++)
        #pragma unroll
        for(int kh=0;kh<2;kh++)
            aq[s][kh] = *(const bf16x8*)(Qb + (size_t)(Rw+s*16+l15)*DIM + h*HD + kh*32 + g*8);

    // exact global row max for q = Rw + s*16 + l15 from the 8 partials
    float crow[2];
    #pragma unroll
    for(int s=0;s<2;s++){
        const int row = Rw + s*16 + l15;
        float m = Pm[(size_t)(h*PMSPLIT+0)*SEQ + row];
        #pragma unroll
        for(int p=1;p<PMSPLIT;p++)
            m = fmaxf(m, Pm[(size_t)(h*PMSPLIT+p)*SEQ + row]);
        crow[s] = 1064986823.0f - k1f*m;
    }

    f32x4 oacc[2][4];
    #pragma unroll
    for(int s=0;s<2;s++)
        #pragma unroll
        for(int d=0;d<4;d++) oacc[s][d] = (f32x4){0.f,0.f,0.f,0.f};
    f32x4 dacc[2];
    dacc[0] = (f32x4){0.f,0.f,0.f,0.f};
    dacc[1] = (f32x4){0.f,0.f,0.f,0.f};

    bf16x8 ones;
    #pragma unroll
    for(int j=0;j<8;j++) ones[j] = (short)0x3F80;   // bf16 1.0

    bf16x8 krA = *(const bf16x8*)(Khh + (size_t)(kbase+sr)*HD + sc*8);
    bf16x8 vrA = *(const bf16x8*)(Vh  + (size_t)sr*SEQP + kbase + sc*8);
    *(bf16x8*)&kb[0][lA] = krA;
    *(bf16x8*)&vb[0][lA] = vrA;
    __syncthreads();

    for(int t=0;t<KTILES;t++){
        const int cur = t & 1;
        if(t+1 < KTILES){
            const int k0n = kbase + (t+1)*64;
            krA = *(const bf16x8*)(Khh + (size_t)(k0n+sr)*HD + sc*8);
            vrA = *(const bf16x8*)(Vh  + (size_t)sr*SEQP + k0n + sc*8);
        }
        // swapped QK^T: S^T = K_tile . Q  (lane: q=s*16+l15, k=ks*16+g*4+r)
        #pragma unroll
        for(int ks=0;ks<4;ks++){
            const int krow = ks*16 + l15;
            bf16x8 b0 = *(const bf16x8*)&kb[cur][krow*64 + ((g     ^ l7)*8)];
            bf16x8 b1 = *(const bf16x8*)&kb[cur][krow*64 + (((4+g) ^ l7)*8)];
            #pragma unroll
            for(int s=0;s<2;s++){
                f32x4 acc = (f32x4){0.f,0.f,0.f,0.f};
                __builtin_amdgcn_s_setprio(1);
                acc = __builtin_amdgcn_mfma_f32_16x16x32_bf16(b0, aq[s][0], acc, 0,0,0);
                acc = __builtin_amdgcn_mfma_f32_16x16x32_bf16(b1, aq[s][1], acc, 0,0,0);
                __builtin_amdgcn_s_setprio(0);
                unsigned int w0, w1;
                {
                    float t0 = fmaf(k1f, acc[0], crow[s]);
                    float t1 = fmaf(k1f, acc[1], crow[s]);
                    float t2 = fmaf(k1f, acc[2], crow[s]);
                    float t3 = fmaf(k1f, acc[3], crow[s]);
                    unsigned int p0 = f2bfh(__int_as_float((int)t0));
                    unsigned int p1 = f2bfh(__int_as_float((int)t1));
                    unsigned int p2 = f2bfh(__int_as_float((int)t2));
                    unsigned int p3 = f2bfh(__int_as_float((int)t3));
                    w0 = p0 | (p1 << 16);
                    w1 = p2 | (p3 << 16);
                }
                u32x2 pw; pw[0] = w0; pw[1] = w1;
                *(u32x2*)&pb[wv][(s*16+l15)*PSTRIDE + ks*16 + g*4] = pw;
            }
        }
        FENCE_LDS();   // wave-local: P writes visible to cross-lane reads

        __builtin_amdgcn_s_setprio(1);
        #pragma unroll
        for(int ks2=0; ks2<2; ks2++){
            bf16x8 pa[2];
            #pragma unroll
            for(int s=0;s<2;s++)
                pa[s] = *(const bf16x8*)&pb[wv][(s*16+l15)*PSTRIDE + ks2*32 + g*8];
            #pragma unroll
            for(int s=0;s<2;s++)
                dacc[s] = __builtin_amdgcn_mfma_f32_16x16x32_bf16(pa[s], ones, dacc[s], 0,0,0);
            #pragma unroll
            for(int d=0;d<4;d++){
                const int vrow = d*16 + l15;
                bf16x8 bv_ = *(const bf16x8*)&vb[cur][vrow*64 + (((ks2*4+g) ^ l7)*8)];
                #pragma unroll
                for(int s=0;s<2;s++)
                    oacc[s][d] = __builtin_amdgcn_mfma_f32_16x16x32_bf16(pa[s], bv_, oacc[s][d], 0,0,0);
            }
        }
        __builtin_amdgcn_s_setprio(0);

        if(t+1 < KTILES){
            *(bf16x8*)&kb[cur^1][lA] = krA;
            *(bf16x8*)&vb[cur^1][lA] = vrA;
        }
        __syncthreads();   // writes to cur^1 visible; reads of cur done blockwide
    }

    // write partial num/den (f32) for the merge kernel
    #pragma unroll
    for(int s=0;s<2;s++)
        #pragma unroll
        for(int d=0;d<4;d++)
            #pragma unroll
            for(int r=0;r<4;r++)
                numf[(size_t)kz*SEQ*DIM + (size_t)(Rw+s*16+g*4+r)*DIM + h*HD + d*16 + l15]
                    = oacc[s][d][r];
    if(l15 == 0){
        #pragma unroll
        for(int s=0;s<2;s++)
            #pragma unroll
            for(int r=0;r<4;r++)
                denf[(size_t)kz*SEQ*NH + (size_t)(Rw+s*16+g*4+r)*NH + h] = dacc[s][r];
    }
}

// ---------------------------------------------------------------------------
// Kernel 2c: merge the 4 key-split partials -> Ab bf16. Fixed order.
// ---------------------------------------------------------------------------
__global__ __launch_bounds__(256) void attn_merge_kernel(
    const float* __restrict__ numf,
    const float* __restrict__ denf,
    unsigned short* __restrict__ Ab)
{
    const size_t NS = (size_t)SEQ*DIM;
    int idx = blockIdx.x*256 + threadIdx.x;   // 0 .. SEQ*DIM/4 - 1
    int row = idx >> 7;                       // DIM/4 = 128 groups per row
    int dg  = (idx & 127) << 2;               // dim start (x4)
    int h   = dg >> 6;

    float d0 = denf[(size_t)0*SEQ*NH + (size_t)row*NH + h];
    float d1 = denf[(size_t)1*SEQ*NH + (size_t)row*NH + h];
    float d2 = denf[(size_t)2*SEQ*NH + (size_t)row*NH + h];
    float d3 = denf[(size_t)3*SEQ*NH + (size_t)row*NH + h];
    float inv = 1.0f / (((d0 + d1) + d2) + d3);

    f32x4 n0 = *(const f32x4*)(numf + 0*NS + (size_t)row*DIM + dg);
    f32x4 n1 = *(const f32x4*)(numf + 1*NS + (size_t)row*DIM + dg);
    f32x4 n2 = *(const f32x4*)(numf + 2*NS + (size_t)row*DIM + dg);
    f32x4 n3 = *(const f32x4*)(numf + 3*NS + (size_t)row*DIM + dg);
    f32x4 s = ((n0 + n1) + n2) + n3;

    s16x4 o;
    #pragma unroll
    for(int j=0;j<4;j++) o[j] = (short)f2bfh(s[j] * inv);
    *(s16x4*)(Ab + (size_t)row*DIM + dg) = o;
}

// ---------------------------------------------------------------------------
// Kernel 2 (fallback): single-kernel two-pass attention if ws too small
// ---------------------------------------------------------------------------
__global__ __launch_bounds__(256, 2) void attn_kernel(
    const unsigned short* __restrict__ Qb,
    const unsigned short* __restrict__ Kh,
    const unsigned short* __restrict__ Vtp,
    unsigned short* __restrict__ Ab,
    float k1f)
{
    __shared__ __align__(16) unsigned short kbf[2][64*64];
    __shared__ __align__(16) unsigned short vbf[2][64*64];
    __shared__ __align__(16) unsigned short pbf[4][16*68];

    const int tid = threadIdx.x;
    const int wv  = tid >> 6;
    const int l   = tid & 63;
    const int g   = l >> 4;
    const int l15 = l & 15;
    const int l7  = l15 & 7;
    const int h   = blockIdx.x & 7;
    const int Rw  = (blockIdx.x >> 3) * 64 + wv * 16;

    const unsigned short* Khh = Kh  + (size_t)h*SEQ*HD;
    const unsigned short* Vh  = Vtp + (size_t)h*HD*SEQP;

    const int sr  = tid >> 3;
    const int sc  = tid & 7;
    const int scs = (sc ^ (sr & 7)) * 8;
    const int ldsA = sr*64 + scs;
    const int ldsB = (sr+32)*64 + scs;

    bf16x8 aq[2];
    #pragma unroll
    for(int kh=0;kh<2;kh++)
        aq[kh] = *(const bf16x8*)(Qb + (size_t)(Rw+l15)*DIM + h*HD + kh*32 + g*8);

    bf16x8 krA, krB, vrA, vrB;

    float mx[4];
    mx[0]=mx[1]=mx[2]=mx[3]=-3.0e38f;

    krA = *(const bf16x8*)(Khh + (size_t)sr*HD      + sc*8);
    krB = *(const bf16x8*)(Khh + (size_t)(sr+32)*HD + sc*8);
    *(bf16x8*)&kbf[0][ldsA] = krA;
    *(bf16x8*)&kbf[0][ldsB] = krB;
    __syncthreads();

    for(int t=0;t<NT;t++){
        const int cur = t & 1;
        if(t+1 < NT){
            const unsigned short* kp = Khh + (size_t)((t+1)*64)*HD;
            krA = *(const bf16x8*)(kp + (size_t)sr*HD      + sc*8);
            krB = *(const bf16x8*)(kp + (size_t)(sr+32)*HD + sc*8);
        }
        #pragma unroll
        for(int ks=0;ks<4;ks++){
            const int krow = ks*16 + l15;
            bf16x8 b0 = *(const bf16x8*)&kbf[cur][krow*64 + ((g     ^ l7)*8)];
            bf16x8 b1 = *(const bf16x8*)&kbf[cur][krow*64 + (((4+g) ^ l7)*8)];
            f32x4 acc = (f32x4){0.f,0.f,0.f,0.f};
            acc = __builtin_amdgcn_mfma_f32_16x16x32_bf16(aq[0], b0, acc, 0,0,0);
            acc = __builtin_amdgcn_mfma_f32_16x16x32_bf16(aq[1], b1, acc, 0,0,0);
            #pragma unroll
            for(int r=0;r<4;r++) mx[r] = fmaxf(mx[r], acc[r]);
        }
        if(t+1 < NT){
            *(bf16x8*)&kbf[cur^1][ldsA] = krA;
            *(bf16x8*)&kbf[cur^1][ldsB] = krB;
        }
        __syncthreads();
    }
    #pragma unroll
    for(int off=1; off<16; off<<=1)
        #pragma unroll
        for(int r=0;r<4;r++)
            mx[r] = fmaxf(mx[r], __shfl_xor(mx[r], off, 64));
    float crow[4];
    #pragma unroll
    for(int r=0;r<4;r++) crow[r] = 1064986823.0f - k1f*mx[r];

    f32x4 oacc[4];
    #pragma unroll
    for(int d=0;d<4;d++) oacc[d] = (f32x4){0.f,0.f,0.f,0.f};
    f32x4 dacc = (f32x4){0.f,0.f,0.f,0.f};

    bf16x8 ones;
    #pragma unroll
    for(int j=0;j<8;j++) ones[j] = (short)0x3F80;

    krA = *(const bf16x8*)(Khh + (size_t)sr*HD        + sc*8);
    krB = *(const bf16x8*)(Khh + (size_t)(sr+32)*HD   + sc*8);
    vrA = *(const bf16x8*)(Vh  + (size_t)sr*SEQP      + sc*8);
    vrB = *(const bf16x8*)(Vh  + (size_t)(sr+32)*SEQP + sc*8);
    *(bf16x8*)&kbf[0][ldsA] = krA;  *(bf16x8*)&kbf[0][ldsB] = krB;
    *(bf16x8*)&vbf[0][ldsA] = vrA;  *(bf16x8*)&vbf[0][ldsB] = vrB;
    __syncthreads();

    for(int t=0;t<NT;t++){
        const int cur = t & 1;
        if(t+1 < NT){
            const int k0n = (t+1)*64;
            krA = *(const bf16x8*)(Khh + (size_t)(k0n + sr)*HD    + sc*8);
            krB = *(const bf16x8*)(Khh + (size_t)(k0n + sr+32)*HD + sc*8);
            vrA = *(const bf16x8*)(Vh  + (size_t)sr*SEQP      + k0n + sc*8);
            vrB = *(const bf16x8*)(Vh  + (size_t)(sr+32)*SEQP + k0n + sc*8);
        }
        #pragma unroll
        for(int ks=0;ks<4;ks++){
            const int krow = ks*16 + l15;
            bf16x8 b0 = *(const bf16x8*)&kbf[cur][krow*64 + ((g     ^ l7)*8)];
            bf16x8 b1 = *(const bf16x8*)&kbf[cur][krow*64 + (((4+g) ^ l7)*8)];
            f32x4 acc = (f32x4){0.f,0.f,0.f,0.f};
            acc = __builtin_amdgcn_mfma_f32_16x16x32_bf16(aq[0], b0, acc, 0,0,0);
            acc = __builtin_amdgcn_mfma_f32_16x16x32_bf16(aq[1], b1, acc, 0,0,0);
            #pragma unroll
            for(int r=0;r<4;r++){
                float tt = fmaf(k1f, acc[r], crow[r]);
                pbf[wv][(g*4+r)*68 + ks*16 + l15] = f2bfh(__int_as_float((int)tt));
            }
        }
        FENCE_LDS();

        #pragma unroll
        for(int ks2=0; ks2<2; ks2++){
            bf16x8 pa = *(const bf16x8*)&pbf[wv][l15*68 + ks2*32 + g*8];
            dacc = __builtin_amdgcn_mfma_f32_16x16x32_bf16(pa, ones, dacc, 0,0,0);
            #pragma unroll
            for(int d=0;d<4;d++){
                const int vrow = d*16 + l15;
                bf16x8 bv_ = *(const bf16x8*)&vbf[cur][vrow*64 + (((ks2*4+g) ^ l7)*8)];
                oacc[d] = __builtin_amdgcn_mfma_f32_16x16x32_bf16(pa, bv_, oacc[d], 0,0,0);
            }
        }
        if(t+1 < NT){
            *(bf16x8*)&kbf[cur^1][ldsA] = krA;  *(bf16x8*)&kbf[cur^1][ldsB] = krB;
            *(bf16x8*)&vbf[cur^1][ldsA] = vrA;  *(bf16x8*)&vbf[cur^1][ldsB] = vrB;
        }
        __syncthreads();
    }

    float inv[4];
    #pragma unroll
    for(int r=0;r<4;r++) inv[r] = 1.0f / dacc[r];
    #pragma unroll
    for(int d=0;d<4;d++)
        #pragma unroll
        for(int r=0;r<4;r++)
            Ab[(size_t)(Rw + g*4 + r)*DIM + h*HD + d*16 + l15] =
                f2bfh(oacc[d][r] * inv[r]);
}

// ---------------------------------------------------------------------------
// Kernel 3: output projection, cooperative LDS staging, f32 Wout converted
// in staging registers (bit-identical to the previous cvt5 path).
// ---------------------------------------------------------------------------
__global__ __launch_bounds__(256, 4) void proj_out_b_kernel(
    const unsigned short* __restrict__ Ab,
    const float* __restrict__ Wout,
    float* __restrict__ out)
{
    __shared__ __align__(16) unsigned short xs[128*64];   // 16KB
    __shared__ __align__(16) unsigned short wsh[64*64];   // 8KB

    const int tid = threadIdx.x;
    const int wv  = tid >> 6;
    const int l   = tid & 63;
    const int g   = l >> 4;
    const int l15 = l & 15;
    const int l7  = l15 & 7;
    const int r0b = blockIdx.x * 128;
    const int c0  = blockIdx.y * 64;

    const int sc  = tid & 7;
    const int sr  = tid >> 3;
    const int scs = (sc ^ (sr & 7)) * 8;

    f32x4 acc[2][4];
    #pragma unroll
    for(int s=0;s<2;s++)
        #pragma unroll
        for(int d=0;d<4;d++) acc[s][d] = (f32x4){0.f,0.f,0.f,0.f};

    bf16x8 xf[4], wf[2];
    #pragma unroll
    for(int j=0;j<4;j++)
        xf[j] = *(const bf16x8*)(Ab + (size_t)(r0b + sr + 32*j)*DIM + sc*8);
    #pragma unroll
    for(int j=0;j<2;j++)
        wf[j] = load8f(Wout + (size_t)(c0 + sr + 32*j)*DIM + sc*8);

    for(int t=0;t<8;t++){
        #pragma unroll
        for(int j=0;j<4;j++)
            *(bf16x8*)&xs[(sr + 32*j)*64 + scs] = xf[j];
        #pragma unroll
        for(int j=0;j<2;j++)
            *(bf16x8*)&wsh[(sr + 32*j)*64 + scs] = wf[j];
        __syncthreads();
        if(t+1 < 8){
            const int kt = (t+1)*64;
            #pragma unroll
            for(int j=0;j<4;j++)
                xf[j] = *(const bf16x8*)(Ab + (size_t)(r0b + sr + 32*j)*DIM + kt + sc*8);
            #pragma unroll
            for(int j=0;j<2;j++)
                wf[j] = load8f(Wout + (size_t)(c0 + sr + 32*j)*DIM + kt + sc*8);
        }
        #pragma unroll
        for(int kh=0;kh<2;kh++){
            bf16x8 a[2];
            #pragma unroll
            for(int s=0;s<2;s++){
                const int row = wv*32 + s*16 + l15;
                a[s] = *(const bf16x8*)&xs[row*64 + (((kh*4+g) ^ l7)*8)];
            }
            #pragma unroll
            for(int d=0;d<4;d++){
                const int row = d*16 + l15;
                bf16x8 b = *(const bf16x8*)&wsh[row*64 + (((kh*4+g) ^ l7)*8)];
                #pragma unroll
                for(int s=0;s<2;s++)
                    acc[s][d] = __builtin_amdgcn_mfma_f32_16x16x32_bf16(a[s], b, acc[s][d], 0,0,0);
            }
        }
        __syncthreads();
    }

    const int r0 = r0b + wv*32;
    #pragma unroll
    for(int s=0;s<2;s++)
        #pragma unroll
        for(int d=0;d<4;d++)
            #pragma unroll
            for(int r=0;r<4;r++)
                out[(size_t)(r0+s*16+g*4+r)*DIM + c0 + d*16 + l15] = acc[s][d][r];
}

// fallback out-proj (unstaged, f32 Wout with in-loop cvt)
__global__ __launch_bounds__(256) void proj_out_kernel(
    const unsigned short* __restrict__ Ab,
    const float* __restrict__ Wout,
    float* __restrict__ out)
{
    const int wv  = threadIdx.x >> 6;
    const int l   = threadIdx.x & 63;
    const int g   = l >> 4;
    const int l15 = l & 15;
    const int r0  = blockIdx.x * 128 + wv * 32;
    const int c0  = blockIdx.y * 64;

    f32x4 acc[2][4];
    #pragma unroll
    for(int s=0;s<2;s++)
        #pragma unroll
        for(int d=0;d<4;d++) acc[s][d] = (f32x4){0.f,0.f,0.f,0.f};

    for(int kt=0; kt<DIM; kt+=32){
        bf16x8 a[2];
        #pragma unroll
        for(int s=0;s<2;s++)
            a[s] = *(const bf16x8*)(Ab + (size_t)(r0+s*16+l15)*DIM + kt + g*8);
        #pragma unroll
        for(int d=0;d<4;d++){
            bf16x8 b = load8f(Wout + (size_t)(c0+d*16+l15)*DIM + kt + g*8);
            #pragma unroll
            for(int s=0;s<2;s++)
                acc[s][d] = __builtin_amdgcn_mfma_f32_16x16x32_bf16(a[s], b, acc[s][d], 0,0,0);
        }
    }

    #pragma unroll
    for(int s=0;s<2;s++)
        #pragma unroll
        for(int d=0;d<4;d++)
            #pragma unroll
            for(int r=0;r<4;r++)
                out[(size_t)(r0+s*16+g*4+r)*DIM + c0 + d*16 + l15] = acc[s][d][r];
}

// ---------------------------------------------------------------------------
extern "C" void kernel_launch(void* const* d_in, const int* in_sizes, int n_in,
                              void* d_out, int out_size, void* d_ws, size_t ws_size,
                              hipStream_t stream)
{
    const float* x    = (const float*)d_in[0];
    const float* Wq   = (const float*)d_in[1];
    const float* bq   = (const float*)d_in[2];
    const float* Wk   = (const float*)d_in[3];
    const float* bk   = (const float*)d_in[4];
    const float* Wv   = (const float*)d_in[5];
    const float* bv   = (const float*)d_in[6];
    const float* Wout = (const float*)d_in[7];
    float* out = (float*)d_out;

    unsigned short* Qb  = (unsigned short*)d_ws;             // [SEQ][DIM]
    unsigned short* Kh  = Qb  + (size_t)SEQ*DIM;             // [NH][SEQ][HD]
    unsigned short* Vtp = Kh  + (size_t)NH*SEQ*HD;           // [NH][HD][SEQP]
    unsigned short* Ab  = Vtp + (size_t)NH*HD*SEQP;          // [SEQ][DIM]
    float* Pm   = (float*)(Ab + (size_t)SEQ*DIM);            // [NH*PMSPLIT][SEQ]
    float* numf = Pm   + (size_t)NH*PMSPLIT*SEQ;             // [4][SEQ][DIM]
    float* denf = numf + (size_t)KSPLIT*SEQ*DIM;             // [4][SEQ][NH]

    const size_t needed_bf16 = ((size_t)SEQ*DIM*3 + (size_t)NH*HD*SEQP) * 2;
    const size_t needed_f32  = ((size_t)NH*PMSPLIT*SEQ + (size_t)KSPLIT*SEQ*DIM
                                + (size_t)KSPLIT*SEQ*NH) * 4;
    const size_t needed_split = needed_bf16 + needed_f32;

    // quake fast inverse sqrt of HEAD_DIM (replicates numpy f32 ops)
    float xx = 64.0f;
    float x2 = xx * 0.5f;
    int ii; memcpy(&ii, &xx, 4);
    ii = 1597463007 - (ii >> 1);
    float y; memcpy(&y, &ii, 4);
    y = y * (1.5f - x2 * y * y);
    const float scaling = y;
    const float k1f = 12102203.17133801f * scaling;   // GIST_A * scaling (f32)

    if(ws_size >= needed_split){
        proj_qkv_b_kernel<<<dim3(SEQ/128, DIM/64, 3), 256, 0, stream>>>(
            x, Wq, bq, Wk, bk, Wv, bv, Qb, Kh, Vtp);
        attn_max_kernel<<<dim3((SEQ/256)*NH*PMSPLIT), 512, 0, stream>>>(Qb, Kh, Pm);
        attn_pv_kernel<<<dim3((SEQ/256)*NH*KSPLIT), 512, 0, stream>>>(
            Qb, Kh, Vtp, Pm, numf, denf, k1f);
        attn_merge_kernel<<<dim3(SEQ*DIM/4/256), 256, 0, stream>>>(numf, denf, Ab);
        proj_out_b_kernel<<<dim3(SEQ/128, DIM/64), 256, 0, stream>>>(Ab, Wout, out);
    } else if(ws_size >= needed_bf16){
        proj_qkv_b_kernel<<<dim3(SEQ/128, DIM/64, 3), 256, 0, stream>>>(
            x, Wq, bq, Wk, bk, Wv, bv, Qb, Kh, Vtp);
        attn_kernel<<<dim3((SEQ/64)*NH), 256, 0, stream>>>(Qb, Kh, Vtp, Ab, k1f);
        proj_out_b_kernel<<<dim3(SEQ/128, DIM/64), 256, 0, stream>>>(Ab, Wout, out);
    } else {
        proj_qkv_kernel<<<dim3(SEQ/128, DIM/64, 3), 256, 0, stream>>>(
            x, Wq, bq, Wk, bk, Wv, bv, Qb, Kh, Vtp);
        attn_kernel<<<dim3((SEQ/64)*NH), 256, 0, stream>>>(Qb, Kh, Vtp, Ab, k1f);
        proj_out_kernel<<<dim3(SEQ/128, DIM/64), 256, 0, stream>>>(Ab, Wout, out);
    }
}

// Round 18
// 98.337 us; speedup vs baseline: 1.0878x; 1.0878x over previous
//
#include <hip/hip_runtime.h>
#include <hip/hip_bf16.h>
#include <string.h>

#define SEQ 4096
#define DIM 512
#define NH  8
#define HD  64
#define SEQP (SEQ + 128)   // padded V row stride
#define NT  (SEQ/64)       // 64-key tiles
#define KSPLIT 4
#define KCHUNK (SEQ/KSPLIT)        // 1024 keys per split (pass B)
#define KTILES (KCHUNK/64)         // 16 tiles per split
#define PMSPLIT 8
#define KCHUNK_A (SEQ/PMSPLIT)     // 512 keys per split (pass A)
#define KTILES_A (KCHUNK_A/64)     // 8 tiles

typedef __attribute__((ext_vector_type(4))) float  f32x4;
typedef __attribute__((ext_vector_type(8))) short  bf16x8;
typedef __attribute__((ext_vector_type(4))) short  s16x4;
typedef __attribute__((ext_vector_type(2))) unsigned int u32x2;

// f32 -> bf16 via hardware convert (RNE on gfx950)
__device__ __forceinline__ unsigned short f2bfh(float f){
    union { __hip_bfloat16 h; unsigned short u; } cv;
    cv.h = __float2bfloat16(f);
    return cv.u;
}

__device__ __forceinline__ bf16x8 cvt8(f32x4 lo, f32x4 hi){
    bf16x8 r;
    r[0]=(short)f2bfh(lo[0]); r[1]=(short)f2bfh(lo[1]);
    r[2]=(short)f2bfh(lo[2]); r[3]=(short)f2bfh(lo[3]);
    r[4]=(short)f2bfh(hi[0]); r[5]=(short)f2bfh(hi[1]);
    r[6]=(short)f2bfh(hi[2]); r[7]=(short)f2bfh(hi[3]);
    return r;
}

__device__ __forceinline__ bf16x8 load8f(const float* p){
    f32x4 lo = *(const f32x4*)p;
    f32x4 hi = *(const f32x4*)(p+4);
    return cvt8(lo, hi);
}

// LDS-only fence: orders this wave's LDS ops; not a VALU/MFMA schedule wall.
#define FENCE_LDS() asm volatile("s_waitcnt lgkmcnt(0)" ::: "memory")

// ---------------------------------------------------------------------------
// Kernel 0: one-time f32 -> bf16 conversion of x and the four weight matrices.
// ---------------------------------------------------------------------------
__global__ __launch_bounds__(256) void cvt5_kernel(
    const float* __restrict__ x,  const float* __restrict__ wq,
    const float* __restrict__ wk, const float* __restrict__ wv,
    const float* __restrict__ wo,
    unsigned short* __restrict__ xb,  unsigned short* __restrict__ wqb,
    unsigned short* __restrict__ wkb, unsigned short* __restrict__ wvb,
    unsigned short* __restrict__ wob)
{
    int b = blockIdx.x;
    const float* src; unsigned short* dst; int base;
    if (b < 1024){ src = x; dst = xb; base = b; }
    else {
        int t  = (b - 1024) >> 7;
        base   = (b - 1024) & 127;
        src = (t==0) ? wq  : (t==1) ? wk  : (t==2) ? wv  : wo;
        dst = (t==0) ? wqb : (t==1) ? wkb : (t==2) ? wvb : wob;
    }
    size_t i = ((size_t)base*256 + threadIdx.x)*8;
    f32x4 lo = *(const f32x4*)(src + i);
    f32x4 hi = *(const f32x4*)(src + i + 4);
    *(bf16x8*)(dst + i) = cvt8(lo, hi);
}

// ---------------------------------------------------------------------------
// Kernel 1 (fast path): fused Q/K/V projections with cooperative LDS staging.
// ---------------------------------------------------------------------------
__global__ __launch_bounds__(256, 4) void proj_qkv_b_kernel(
    const unsigned short* __restrict__ xb,
    const unsigned short* __restrict__ Wqb, const float* __restrict__ bq,
    const unsigned short* __restrict__ Wkb, const float* __restrict__ bk,
    const unsigned short* __restrict__ Wvb, const float* __restrict__ bv,
    unsigned short* __restrict__ Qb, unsigned short* __restrict__ Kh,
    unsigned short* __restrict__ Vtp)
{
    __shared__ __align__(16) unsigned short xs[128*64];   // 16KB
    __shared__ __align__(16) unsigned short wsh[64*64];   // 8KB

    const int z = blockIdx.z;
    const unsigned short* W = (z==0) ? Wqb : ((z==1) ? Wkb : Wvb);
    const float* bb = (z==0) ? bq : ((z==1) ? bk : bv);
    const int tid = threadIdx.x;
    const int wv  = tid >> 6;
    const int l   = tid & 63;
    const int g   = l >> 4;
    const int l15 = l & 15;
    const int l7  = l15 & 7;
    const int r0b = blockIdx.x * 128;
    const int c0  = blockIdx.y * 64;
    const int hy  = blockIdx.y;

    const int sc  = tid & 7;
    const int sr  = tid >> 3;                 // 0..31
    const int scs = (sc ^ (sr & 7)) * 8;      // swizzled granule offset

    f32x4 acc[2][4];
    #pragma unroll
    for(int s=0;s<2;s++)
        #pragma unroll
        for(int d=0;d<4;d++) acc[s][d] = (f32x4){0.f,0.f,0.f,0.f};

    bf16x8 xf[4], wf[2];
    #pragma unroll
    for(int j=0;j<4;j++)
        xf[j] = *(const bf16x8*)(xb + (size_t)(r0b + sr + 32*j)*DIM + sc*8);
    #pragma unroll
    for(int j=0;j<2;j++)
        wf[j] = *(const bf16x8*)(W + (size_t)(c0 + sr + 32*j)*DIM + sc*8);

    for(int t=0;t<8;t++){
        #pragma unroll
        for(int j=0;j<4;j++)
            *(bf16x8*)&xs[(sr + 32*j)*64 + scs] = xf[j];
        #pragma unroll
        for(int j=0;j<2;j++)
            *(bf16x8*)&wsh[(sr + 32*j)*64 + scs] = wf[j];
        __syncthreads();
        if(t+1 < 8){
            const int kt = (t+1)*64;
            #pragma unroll
            for(int j=0;j<4;j++)
                xf[j] = *(const bf16x8*)(xb + (size_t)(r0b + sr + 32*j)*DIM + kt + sc*8);
            #pragma unroll
            for(int j=0;j<2;j++)
                wf[j] = *(const bf16x8*)(W + (size_t)(c0 + sr + 32*j)*DIM + kt + sc*8);
        }
        #pragma unroll
        for(int kh=0;kh<2;kh++){
            bf16x8 a[2];
            #pragma unroll
            for(int s=0;s<2;s++){
                const int row = wv*32 + s*16 + l15;
                a[s] = *(const bf16x8*)&xs[row*64 + (((kh*4+g) ^ l7)*8)];
            }
            #pragma unroll
            for(int d=0;d<4;d++){
                const int row = d*16 + l15;
                bf16x8 b = *(const bf16x8*)&wsh[row*64 + (((kh*4+g) ^ l7)*8)];
                #pragma unroll
                for(int s=0;s<2;s++)
                    acc[s][d] = __builtin_amdgcn_mfma_f32_16x16x32_bf16(a[s], b, acc[s][d], 0,0,0);
            }
        }
        __syncthreads();
    }

    const int r0 = r0b + wv*32;
    #pragma unroll
    for(int d=0;d<4;d++){
        float bias = bb[c0 + d*16 + l15];
        #pragma unroll
        for(int s=0;s<2;s++){
            if(z == 2){
                s16x4 pk;
                #pragma unroll
                for(int r=0;r<4;r++) pk[r] = (short)f2bfh(acc[s][d][r] + bias);
                *(s16x4*)(Vtp + ((size_t)hy*HD + d*16+l15)*SEQP + r0 + s*16 + g*4) = pk;
            } else if(z == 1){
                #pragma unroll
                for(int r=0;r<4;r++)
                    Kh[((size_t)hy*SEQ + r0+s*16+g*4+r)*HD + d*16 + l15] =
                        f2bfh(acc[s][d][r] + bias);
            } else {
                #pragma unroll
                for(int r=0;r<4;r++)
                    Qb[(size_t)(r0+s*16+g*4+r)*DIM + c0 + d*16 + l15] =
                        f2bfh(acc[s][d][r] + bias);
            }
        }
    }
}

// ---------------------------------------------------------------------------
// Kernel 1 (fallback): unstaged, f32 weights with in-loop cvt
// ---------------------------------------------------------------------------
__global__ __launch_bounds__(256) void proj_qkv_kernel(
    const float* __restrict__ x,
    const float* __restrict__ Wq, const float* __restrict__ bq,
    const float* __restrict__ Wk, const float* __restrict__ bk,
    const float* __restrict__ Wv, const float* __restrict__ bv,
    unsigned short* __restrict__ Qb, unsigned short* __restrict__ Kh,
    unsigned short* __restrict__ Vtp)
{
    const int z = blockIdx.z;
    const float* W  = (z==0) ? Wq : ((z==1) ? Wk : Wv);
    const float* bb = (z==0) ? bq : ((z==1) ? bk : bv);
    const int wv  = threadIdx.x >> 6;
    const int l   = threadIdx.x & 63;
    const int g   = l >> 4;
    const int l15 = l & 15;
    const int r0  = blockIdx.x * 128 + wv * 32;
    const int c0  = blockIdx.y * 64;
    const int hy  = blockIdx.y;

    f32x4 acc[2][4];
    #pragma unroll
    for(int s=0;s<2;s++)
        #pragma unroll
        for(int d=0;d<4;d++) acc[s][d] = (f32x4){0.f,0.f,0.f,0.f};

    for(int kt=0; kt<DIM; kt+=32){
        bf16x8 a[2];
        #pragma unroll
        for(int s=0;s<2;s++)
            a[s] = load8f(x + (size_t)(r0+s*16+l15)*DIM + kt + g*8);
        #pragma unroll
        for(int d=0;d<4;d++){
            bf16x8 b = load8f(W + (size_t)(c0+d*16+l15)*DIM + kt + g*8);
            #pragma unroll
            for(int s=0;s<2;s++)
                acc[s][d] = __builtin_amdgcn_mfma_f32_16x16x32_bf16(a[s], b, acc[s][d], 0,0,0);
        }
    }

    #pragma unroll
    for(int d=0;d<4;d++){
        float bias = bb[c0 + d*16 + l15];
        #pragma unroll
        for(int s=0;s<2;s++){
            if(z == 2){
                s16x4 pk;
                #pragma unroll
                for(int r=0;r<4;r++) pk[r] = (short)f2bfh(acc[s][d][r] + bias);
                *(s16x4*)(Vtp + ((size_t)hy*HD + d*16+l15)*SEQP + r0 + s*16 + g*4) = pk;
            } else if(z == 1){
                #pragma unroll
                for(int r=0;r<4;r++)
                    Kh[((size_t)hy*SEQ + r0+s*16+g*4+r)*HD + d*16 + l15] =
                        f2bfh(acc[s][d][r] + bias);
            } else {
                #pragma unroll
                for(int r=0;r<4;r++)
                    Qb[(size_t)(r0+s*16+g*4+r)*DIM + c0 + d*16 + l15] =
                        f2bfh(acc[s][d][r] + bias);
            }
        }
    }
}

// ---------------------------------------------------------------------------
// Kernel 2a: pass A (row max), 8-way key-split, swapped QK^T, 32-row waves,
// 8 waves/block (256 q-rows), double-buffered K, ONE barrier per tile.
// ---------------------------------------------------------------------------
__global__ __launch_bounds__(512, 4) void attn_max_kernel(
    const unsigned short* __restrict__ Qb,
    const unsigned short* __restrict__ Kh,
    float* __restrict__ Pm)
{
    __shared__ __align__(16) unsigned short kb[2][64*64];   // 16KB

    const int tid = threadIdx.x;
    const int wv  = tid >> 6;
    const int l   = tid & 63;
    const int g   = l >> 4;
    const int l15 = l & 15;
    const int l7  = l15 & 7;
    const int h   = blockIdx.x & 7;
    const int kz  = (blockIdx.x >> 3) & 7;
    const int Rw  = (blockIdx.x >> 6) * 256 + wv * 32;
    const int kbase = kz * KCHUNK_A;

    const unsigned short* Khh = Kh + (size_t)h*SEQ*HD;
    const int sr  = tid >> 3, sc = tid & 7;   // sr 0..63
    const int scs = (sc ^ (sr & 7)) * 8;
    const int lA  = sr*64 + scs;

    bf16x8 aq[2][2];
    #pragma unroll
    for(int s=0;s<2;s++)
        #pragma unroll
        for(int kh=0;kh<2;kh++)
            aq[s][kh] = *(const bf16x8*)(Qb + (size_t)(Rw+s*16+l15)*DIM + h*HD + kh*32 + g*8);

    float mx[2];
    mx[0] = mx[1] = -3.0e38f;

    bf16x8 krA = *(const bf16x8*)(Khh + (size_t)(kbase+sr)*HD + sc*8);
    *(bf16x8*)&kb[0][lA] = krA;
    __syncthreads();

    for(int t=0;t<KTILES_A;t++){
        const int cur = t & 1;
        if(t+1 < KTILES_A)
            krA = *(const bf16x8*)(Khh + (size_t)(kbase+(t+1)*64+sr)*HD + sc*8);
        #pragma unroll
        for(int ks=0;ks<4;ks++){
            const int krow = ks*16 + l15;
            bf16x8 b0 = *(const bf16x8*)&kb[cur][krow*64 + ((g     ^ l7)*8)];
            bf16x8 b1 = *(const bf16x8*)&kb[cur][krow*64 + (((4+g) ^ l7)*8)];
            __builtin_amdgcn_s_setprio(1);
            #pragma unroll
            for(int s=0;s<2;s++){
                f32x4 acc = (f32x4){0.f,0.f,0.f,0.f};
                acc = __builtin_amdgcn_mfma_f32_16x16x32_bf16(b0, aq[s][0], acc, 0,0,0);
                acc = __builtin_amdgcn_mfma_f32_16x16x32_bf16(b1, aq[s][1], acc, 0,0,0);
                #pragma unroll
                for(int r=0;r<4;r++) mx[s] = fmaxf(mx[s], acc[r]);
            }
            __builtin_amdgcn_s_setprio(0);
        }
        if(t+1 < KTILES_A)
            *(bf16x8*)&kb[cur^1][lA] = krA;
        __syncthreads();
    }
    #pragma unroll
    for(int s=0;s<2;s++){
        mx[s] = fmaxf(mx[s], __shfl_xor(mx[s], 16, 64));
        mx[s] = fmaxf(mx[s], __shfl_xor(mx[s], 32, 64));
    }

    if(l < 16){
        Pm[(size_t)(h*PMSPLIT + kz)*SEQ + Rw + l15]      = mx[0];
        Pm[(size_t)(h*PMSPLIT + kz)*SEQ + Rw + 16 + l15] = mx[1];
    }
}

// ---------------------------------------------------------------------------
// Kernel 2b: pass B (fexp + PV), 4-way key-split, swapped QK^T, 32-row waves,
// 8 waves/block, double-buffered K/V, ONE barrier per tile.
// setprio around BOTH QK^T and PV MFMA clusters (best configuration).
// ---------------------------------------------------------------------------
#define PSTRIDE 68

__global__ __launch_bounds__(512, 4) void attn_pv_kernel(
    const unsigned short* __restrict__ Qb,
    const unsigned short* __restrict__ Kh,
    const unsigned short* __restrict__ Vtp,
    const float* __restrict__ Pm,
    float* __restrict__ numf,
    float* __restrict__ denf,
    float k1f)   // GIST_A * scaling
{
    __shared__ __align__(16) unsigned short kb[2][64*64];      // 16KB
    __shared__ __align__(16) unsigned short vb[2][64*64];      // 16KB
    __shared__ __align__(16) unsigned short pb[8][32*PSTRIDE]; // 34.8KB

    const int tid = threadIdx.x;
    const int wv  = tid >> 6;
    const int l   = tid & 63;
    const int g   = l >> 4;
    const int l15 = l & 15;
    const int l7  = l15 & 7;
    const int h   = blockIdx.x & 7;
    const int kz  = (blockIdx.x >> 3) & 3;
    const int Rw  = (blockIdx.x >> 5) * 256 + wv * 32;
    const int kbase = kz * KCHUNK;

    const unsigned short* Khh = Kh  + (size_t)h*SEQ*HD;
    const unsigned short* Vh  = Vtp + (size_t)h*HD*SEQP;

    const int sr  = tid >> 3, sc = tid & 7;   // sr 0..63
    const int scs = (sc ^ (sr & 7)) * 8;
    const int lA  = sr*64 + scs;

    bf16x8 aq[2][2];
    #pragma unroll
    for(int s=0;s<2;s++)
        #pragma unroll
        for(int kh=0;kh<2;kh++)
            aq[s][kh] = *(const bf16x8*)(Qb + (size_t)(Rw+s*16+l15)*DIM + h*HD + kh*32 + g*8);

    // exact global row max for q = Rw + s*16 + l15 from the 8 partials
    float crow[2];
    #pragma unroll
    for(int s=0;s<2;s++){
        const int row = Rw + s*16 + l15;
        float m = Pm[(size_t)(h*PMSPLIT+0)*SEQ + row];
        #pragma unroll
        for(int p=1;p<PMSPLIT;p++)
            m = fmaxf(m, Pm[(size_t)(h*PMSPLIT+p)*SEQ + row]);
        crow[s] = 1064986823.0f - k1f*m;
    }

    f32x4 oacc[2][4];
    #pragma unroll
    for(int s=0;s<2;s++)
        #pragma unroll
        for(int d=0;d<4;d++) oacc[s][d] = (f32x4){0.f,0.f,0.f,0.f};
    f32x4 dacc[2];
    dacc[0] = (f32x4){0.f,0.f,0.f,0.f};
    dacc[1] = (f32x4){0.f,0.f,0.f,0.f};

    bf16x8 ones;
    #pragma unroll
    for(int j=0;j<8;j++) ones[j] = (short)0x3F80;   // bf16 1.0

    bf16x8 krA = *(const bf16x8*)(Khh + (size_t)(kbase+sr)*HD + sc*8);
    bf16x8 vrA = *(const bf16x8*)(Vh  + (size_t)sr*SEQP + kbase + sc*8);
    *(bf16x8*)&kb[0][lA] = krA;
    *(bf16x8*)&vb[0][lA] = vrA;
    __syncthreads();

    for(int t=0;t<KTILES;t++){
        const int cur = t & 1;
        if(t+1 < KTILES){
            const int k0n = kbase + (t+1)*64;
            krA = *(const bf16x8*)(Khh + (size_t)(k0n+sr)*HD + sc*8);
            vrA = *(const bf16x8*)(Vh  + (size_t)sr*SEQP + k0n + sc*8);
        }
        // swapped QK^T: S^T = K_tile . Q  (lane: q=s*16+l15, k=ks*16+g*4+r)
        #pragma unroll
        for(int ks=0;ks<4;ks++){
            const int krow = ks*16 + l15;
            bf16x8 b0 = *(const bf16x8*)&kb[cur][krow*64 + ((g     ^ l7)*8)];
            bf16x8 b1 = *(const bf16x8*)&kb[cur][krow*64 + (((4+g) ^ l7)*8)];
            #pragma unroll
            for(int s=0;s<2;s++){
                f32x4 acc = (f32x4){0.f,0.f,0.f,0.f};
                __builtin_amdgcn_s_setprio(1);
                acc = __builtin_amdgcn_mfma_f32_16x16x32_bf16(b0, aq[s][0], acc, 0,0,0);
                acc = __builtin_amdgcn_mfma_f32_16x16x32_bf16(b1, aq[s][1], acc, 0,0,0);
                __builtin_amdgcn_s_setprio(0);
                unsigned int w0, w1;
                {
                    float t0 = fmaf(k1f, acc[0], crow[s]);
                    float t1 = fmaf(k1f, acc[1], crow[s]);
                    float t2 = fmaf(k1f, acc[2], crow[s]);
                    float t3 = fmaf(k1f, acc[3], crow[s]);
                    unsigned int p0 = f2bfh(__int_as_float((int)t0));
                    unsigned int p1 = f2bfh(__int_as_float((int)t1));
                    unsigned int p2 = f2bfh(__int_as_float((int)t2));
                    unsigned int p3 = f2bfh(__int_as_float((int)t3));
                    w0 = p0 | (p1 << 16);
                    w1 = p2 | (p3 << 16);
                }
                u32x2 pw; pw[0] = w0; pw[1] = w1;
                *(u32x2*)&pb[wv][(s*16+l15)*PSTRIDE + ks*16 + g*4] = pw;
            }
        }
        FENCE_LDS();   // wave-local: P writes visible to cross-lane reads

        __builtin_amdgcn_s_setprio(1);
        #pragma unroll
        for(int ks2=0; ks2<2; ks2++){
            bf16x8 pa[2];
            #pragma unroll
            for(int s=0;s<2;s++)
                pa[s] = *(const bf16x8*)&pb[wv][(s*16+l15)*PSTRIDE + ks2*32 + g*8];
            #pragma unroll
            for(int s=0;s<2;s++)
                dacc[s] = __builtin_amdgcn_mfma_f32_16x16x32_bf16(pa[s], ones, dacc[s], 0,0,0);
            #pragma unroll
            for(int d=0;d<4;d++){
                const int vrow = d*16 + l15;
                bf16x8 bv_ = *(const bf16x8*)&vb[cur][vrow*64 + (((ks2*4+g) ^ l7)*8)];
                #pragma unroll
                for(int s=0;s<2;s++)
                    oacc[s][d] = __builtin_amdgcn_mfma_f32_16x16x32_bf16(pa[s], bv_, oacc[s][d], 0,0,0);
            }
        }
        __builtin_amdgcn_s_setprio(0);

        if(t+1 < KTILES){
            *(bf16x8*)&kb[cur^1][lA] = krA;
            *(bf16x8*)&vb[cur^1][lA] = vrA;
        }
        __syncthreads();   // writes to cur^1 visible; reads of cur done blockwide
    }

    // write partial num/den (f32) for the merge kernel
    #pragma unroll
    for(int s=0;s<2;s++)
        #pragma unroll
        for(int d=0;d<4;d++)
            #pragma unroll
            for(int r=0;r<4;r++)
                numf[(size_t)kz*SEQ*DIM + (size_t)(Rw+s*16+g*4+r)*DIM + h*HD + d*16 + l15]
                    = oacc[s][d][r];
    if(l15 == 0){
        #pragma unroll
        for(int s=0;s<2;s++)
            #pragma unroll
            for(int r=0;r<4;r++)
                denf[(size_t)kz*SEQ*NH + (size_t)(Rw+s*16+g*4+r)*NH + h] = dacc[s][r];
    }
}

// ---------------------------------------------------------------------------
// Kernel 2c: merge the 4 key-split partials -> Ab bf16. Fixed order.
// ---------------------------------------------------------------------------
__global__ __launch_bounds__(256) void attn_merge_kernel(
    const float* __restrict__ numf,
    const float* __restrict__ denf,
    unsigned short* __restrict__ Ab)
{
    const size_t NS = (size_t)SEQ*DIM;
    int idx = blockIdx.x*256 + threadIdx.x;   // 0 .. SEQ*DIM/4 - 1
    int row = idx >> 7;                       // DIM/4 = 128 groups per row
    int dg  = (idx & 127) << 2;               // dim start (x4)
    int h   = dg >> 6;

    float d0 = denf[(size_t)0*SEQ*NH + (size_t)row*NH + h];
    float d1 = denf[(size_t)1*SEQ*NH + (size_t)row*NH + h];
    float d2 = denf[(size_t)2*SEQ*NH + (size_t)row*NH + h];
    float d3 = denf[(size_t)3*SEQ*NH + (size_t)row*NH + h];
    float inv = 1.0f / (((d0 + d1) + d2) + d3);

    f32x4 n0 = *(const f32x4*)(numf + 0*NS + (size_t)row*DIM + dg);
    f32x4 n1 = *(const f32x4*)(numf + 1*NS + (size_t)row*DIM + dg);
    f32x4 n2 = *(const f32x4*)(numf + 2*NS + (size_t)row*DIM + dg);
    f32x4 n3 = *(const f32x4*)(numf + 3*NS + (size_t)row*DIM + dg);
    f32x4 s = ((n0 + n1) + n2) + n3;

    s16x4 o;
    #pragma unroll
    for(int j=0;j<4;j++) o[j] = (short)f2bfh(s[j] * inv);
    *(s16x4*)(Ab + (size_t)row*DIM + dg) = o;
}

// ---------------------------------------------------------------------------
// Kernel 2 (fallback): single-kernel two-pass attention if ws too small
// ---------------------------------------------------------------------------
__global__ __launch_bounds__(256, 2) void attn_kernel(
    const unsigned short* __restrict__ Qb,
    const unsigned short* __restrict__ Kh,
    const unsigned short* __restrict__ Vtp,
    unsigned short* __restrict__ Ab,
    float k1f)
{
    __shared__ __align__(16) unsigned short kbf[2][64*64];
    __shared__ __align__(16) unsigned short vbf[2][64*64];
    __shared__ __align__(16) unsigned short pbf[4][16*68];

    const int tid = threadIdx.x;
    const int wv  = tid >> 6;
    const int l   = tid & 63;
    const int g   = l >> 4;
    const int l15 = l & 15;
    const int l7  = l15 & 7;
    const int h   = blockIdx.x & 7;
    const int Rw  = (blockIdx.x >> 3) * 64 + wv * 16;

    const unsigned short* Khh = Kh  + (size_t)h*SEQ*HD;
    const unsigned short* Vh  = Vtp + (size_t)h*HD*SEQP;

    const int sr  = tid >> 3;
    const int sc  = tid & 7;
    const int scs = (sc ^ (sr & 7)) * 8;
    const int ldsA = sr*64 + scs;
    const int ldsB = (sr+32)*64 + scs;

    bf16x8 aq[2];
    #pragma unroll
    for(int kh=0;kh<2;kh++)
        aq[kh] = *(const bf16x8*)(Qb + (size_t)(Rw+l15)*DIM + h*HD + kh*32 + g*8);

    bf16x8 krA, krB, vrA, vrB;

    float mx[4];
    mx[0]=mx[1]=mx[2]=mx[3]=-3.0e38f;

    krA = *(const bf16x8*)(Khh + (size_t)sr*HD      + sc*8);
    krB = *(const bf16x8*)(Khh + (size_t)(sr+32)*HD + sc*8);
    *(bf16x8*)&kbf[0][ldsA] = krA;
    *(bf16x8*)&kbf[0][ldsB] = krB;
    __syncthreads();

    for(int t=0;t<NT;t++){
        const int cur = t & 1;
        if(t+1 < NT){
            const unsigned short* kp = Khh + (size_t)((t+1)*64)*HD;
            krA = *(const bf16x8*)(kp + (size_t)sr*HD      + sc*8);
            krB = *(const bf16x8*)(kp + (size_t)(sr+32)*HD + sc*8);
        }
        #pragma unroll
        for(int ks=0;ks<4;ks++){
            const int krow = ks*16 + l15;
            bf16x8 b0 = *(const bf16x8*)&kbf[cur][krow*64 + ((g     ^ l7)*8)];
            bf16x8 b1 = *(const bf16x8*)&kbf[cur][krow*64 + (((4+g) ^ l7)*8)];
            f32x4 acc = (f32x4){0.f,0.f,0.f,0.f};
            acc = __builtin_amdgcn_mfma_f32_16x16x32_bf16(aq[0], b0, acc, 0,0,0);
            acc = __builtin_amdgcn_mfma_f32_16x16x32_bf16(aq[1], b1, acc, 0,0,0);
            #pragma unroll
            for(int r=0;r<4;r++) mx[r] = fmaxf(mx[r], acc[r]);
        }
        if(t+1 < NT){
            *(bf16x8*)&kbf[cur^1][ldsA] = krA;
            *(bf16x8*)&kbf[cur^1][ldsB] = krB;
        }
        __syncthreads();
    }
    #pragma unroll
    for(int off=1; off<16; off<<=1)
        #pragma unroll
        for(int r=0;r<4;r++)
            mx[r] = fmaxf(mx[r], __shfl_xor(mx[r], off, 64));
    float crow[4];
    #pragma unroll
    for(int r=0;r<4;r++) crow[r] = 1064986823.0f - k1f*mx[r];

    f32x4 oacc[4];
    #pragma unroll
    for(int d=0;d<4;d++) oacc[d] = (f32x4){0.f,0.f,0.f,0.f};
    f32x4 dacc = (f32x4){0.f,0.f,0.f,0.f};

    bf16x8 ones;
    #pragma unroll
    for(int j=0;j<8;j++) ones[j] = (short)0x3F80;

    krA = *(const bf16x8*)(Khh + (size_t)sr*HD        + sc*8);
    krB = *(const bf16x8*)(Khh + (size_t)(sr+32)*HD   + sc*8);
    vrA = *(const bf16x8*)(Vh  + (size_t)sr*SEQP      + sc*8);
    vrB = *(const bf16x8*)(Vh  + (size_t)(sr+32)*SEQP + sc*8);
    *(bf16x8*)&kbf[0][ldsA] = krA;  *(bf16x8*)&kbf[0][ldsB] = krB;
    *(bf16x8*)&vbf[0][ldsA] = vrA;  *(bf16x8*)&vbf[0][ldsB] = vrB;
    __syncthreads();

    for(int t=0;t<NT;t++){
        const int cur = t & 1;
        if(t+1 < NT){
            const int k0n = (t+1)*64;
            krA = *(const bf16x8*)(Khh + (size_t)(k0n + sr)*HD    + sc*8);
            krB = *(const bf16x8*)(Khh + (size_t)(k0n + sr+32)*HD + sc*8);
            vrA = *(const bf16x8*)(Vh  + (size_t)sr*SEQP      + k0n + sc*8);
            vrB = *(const bf16x8*)(Vh  + (size_t)(sr+32)*SEQP + k0n + sc*8);
        }
        #pragma unroll
        for(int ks=0;ks<4;ks++){
            const int krow = ks*16 + l15;
            bf16x8 b0 = *(const bf16x8*)&kbf[cur][krow*64 + ((g     ^ l7)*8)];
            bf16x8 b1 = *(const bf16x8*)&kbf[cur][krow*64 + (((4+g) ^ l7)*8)];
            f32x4 acc = (f32x4){0.f,0.f,0.f,0.f};
            acc = __builtin_amdgcn_mfma_f32_16x16x32_bf16(aq[0], b0, acc, 0,0,0);
            acc = __builtin_amdgcn_mfma_f32_16x16x32_bf16(aq[1], b1, acc, 0,0,0);
            #pragma unroll
            for(int r=0;r<4;r++){
                float tt = fmaf(k1f, acc[r], crow[r]);
                pbf[wv][(g*4+r)*68 + ks*16 + l15] = f2bfh(__int_as_float((int)tt));
            }
        }
        FENCE_LDS();

        #pragma unroll
        for(int ks2=0; ks2<2; ks2++){
            bf16x8 pa = *(const bf16x8*)&pbf[wv][l15*68 + ks2*32 + g*8];
            dacc = __builtin_amdgcn_mfma_f32_16x16x32_bf16(pa, ones, dacc, 0,0,0);
            #pragma unroll
            for(int d=0;d<4;d++){
                const int vrow = d*16 + l15;
                bf16x8 bv_ = *(const bf16x8*)&vbf[cur][vrow*64 + (((ks2*4+g) ^ l7)*8)];
                oacc[d] = __builtin_amdgcn_mfma_f32_16x16x32_bf16(pa, bv_, oacc[d], 0,0,0);
            }
        }
        if(t+1 < NT){
            *(bf16x8*)&kbf[cur^1][ldsA] = krA;  *(bf16x8*)&kbf[cur^1][ldsB] = krB;
            *(bf16x8*)&vbf[cur^1][ldsA] = vrA;  *(bf16x8*)&vbf[cur^1][ldsB] = vrB;
        }
        __syncthreads();
    }

    float inv[4];
    #pragma unroll
    for(int r=0;r<4;r++) inv[r] = 1.0f / dacc[r];
    #pragma unroll
    for(int d=0;d<4;d++)
        #pragma unroll
        for(int r=0;r<4;r++)
            Ab[(size_t)(Rw + g*4 + r)*DIM + h*HD + d*16 + l15] =
                f2bfh(oacc[d][r] * inv[r]);
}

// ---------------------------------------------------------------------------
// Kernel 3 (fast path): output projection, cooperative LDS staging.
// ---------------------------------------------------------------------------
__global__ __launch_bounds__(256, 4) void proj_out_b_kernel(
    const unsigned short* __restrict__ Ab,
    const unsigned short* __restrict__ Wob,
    float* __restrict__ out)
{
    __shared__ __align__(16) unsigned short xs[128*64];   // 16KB
    __shared__ __align__(16) unsigned short wsh[64*64];   // 8KB

    const int tid = threadIdx.x;
    const int wv  = tid >> 6;
    const int l   = tid & 63;
    const int g   = l >> 4;
    const int l15 = l & 15;
    const int l7  = l15 & 7;
    const int r0b = blockIdx.x * 128;
    const int c0  = blockIdx.y * 64;

    const int sc  = tid & 7;
    const int sr  = tid >> 3;
    const int scs = (sc ^ (sr & 7)) * 8;

    f32x4 acc[2][4];
    #pragma unroll
    for(int s=0;s<2;s++)
        #pragma unroll
        for(int d=0;d<4;d++) acc[s][d] = (f32x4){0.f,0.f,0.f,0.f};

    bf16x8 xf[4], wf[2];
    #pragma unroll
    for(int j=0;j<4;j++)
        xf[j] = *(const bf16x8*)(Ab + (size_t)(r0b + sr + 32*j)*DIM + sc*8);
    #pragma unroll
    for(int j=0;j<2;j++)
        wf[j] = *(const bf16x8*)(Wob + (size_t)(c0 + sr + 32*j)*DIM + sc*8);

    for(int t=0;t<8;t++){
        #pragma unroll
        for(int j=0;j<4;j++)
            *(bf16x8*)&xs[(sr + 32*j)*64 + scs] = xf[j];
        #pragma unroll
        for(int j=0;j<2;j++)
            *(bf16x8*)&wsh[(sr + 32*j)*64 + scs] = wf[j];
        __syncthreads();
        if(t+1 < 8){
            const int kt = (t+1)*64;
            #pragma unroll
            for(int j=0;j<4;j++)
                xf[j] = *(const bf16x8*)(Ab + (size_t)(r0b + sr + 32*j)*DIM + kt + sc*8);
            #pragma unroll
            for(int j=0;j<2;j++)
                wf[j] = *(const bf16x8*)(Wob + (size_t)(c0 + sr + 32*j)*DIM + kt + sc*8);
        }
        #pragma unroll
        for(int kh=0;kh<2;kh++){
            bf16x8 a[2];
            #pragma unroll
            for(int s=0;s<2;s++){
                const int row = wv*32 + s*16 + l15;
                a[s] = *(const bf16x8*)&xs[row*64 + (((kh*4+g) ^ l7)*8)];
            }
            #pragma unroll
            for(int d=0;d<4;d++){
                const int row = d*16 + l15;
                bf16x8 b = *(const bf16x8*)&wsh[row*64 + (((kh*4+g) ^ l7)*8)];
                #pragma unroll
                for(int s=0;s<2;s++)
                    acc[s][d] = __builtin_amdgcn_mfma_f32_16x16x32_bf16(a[s], b, acc[s][d], 0,0,0);
            }
        }
        __syncthreads();
    }

    const int r0 = r0b + wv*32;
    #pragma unroll
    for(int s=0;s<2;s++)
        #pragma unroll
        for(int d=0;d<4;d++)
            #pragma unroll
            for(int r=0;r<4;r++)
                out[(size_t)(r0+s*16+g*4+r)*DIM + c0 + d*16 + l15] = acc[s][d][r];
}

// fallback out-proj (f32 Wout with in-loop cvt)
__global__ __launch_bounds__(256) void proj_out_kernel(
    const unsigned short* __restrict__ Ab,
    const float* __restrict__ Wout,
    float* __restrict__ out)
{
    const int wv  = threadIdx.x >> 6;
    const int l   = threadIdx.x & 63;
    const int g   = l >> 4;
    const int l15 = l & 15;
    const int r0  = blockIdx.x * 128 + wv * 32;
    const int c0  = blockIdx.y * 64;

    f32x4 acc[2][4];
    #pragma unroll
    for(int s=0;s<2;s++)
        #pragma unroll
        for(int d=0;d<4;d++) acc[s][d] = (f32x4){0.f,0.f,0.f,0.f};

    for(int kt=0; kt<DIM; kt+=32){
        bf16x8 a[2];
        #pragma unroll
        for(int s=0;s<2;s++)
            a[s] = *(const bf16x8*)(Ab + (size_t)(r0+s*16+l15)*DIM + kt + g*8);
        #pragma unroll
        for(int d=0;d<4;d++){
            bf16x8 b = load8f(Wout + (size_t)(c0+d*16+l15)*DIM + kt + g*8);
            #pragma unroll
            for(int s=0;s<2;s++)
                acc[s][d] = __builtin_amdgcn_mfma_f32_16x16x32_bf16(a[s], b, acc[s][d], 0,0,0);
        }
    }

    #pragma unroll
    for(int s=0;s<2;s++)
        #pragma unroll
        for(int d=0;d<4;d++)
            #pragma unroll
            for(int r=0;r<4;r++)
                out[(size_t)(r0+s*16+g*4+r)*DIM + c0 + d*16 + l15] = acc[s][d][r];
}

// ---------------------------------------------------------------------------
extern "C" void kernel_launch(void* const* d_in, const int* in_sizes, int n_in,
                              void* d_out, int out_size, void* d_ws, size_t ws_size,
                              hipStream_t stream)
{
    const float* x    = (const float*)d_in[0];
    const float* Wq   = (const float*)d_in[1];
    const float* bq   = (const float*)d_in[2];
    const float* Wk   = (const float*)d_in[3];
    const float* bk   = (const float*)d_in[4];
    const float* Wv   = (const float*)d_in[5];
    const float* bv   = (const float*)d_in[6];
    const float* Wout = (const float*)d_in[7];
    float* out = (float*)d_out;

    unsigned short* Qb  = (unsigned short*)d_ws;             // [SEQ][DIM]
    unsigned short* Kh  = Qb  + (size_t)SEQ*DIM;             // [NH][SEQ][HD]
    unsigned short* Vtp = Kh  + (size_t)NH*SEQ*HD;           // [NH][HD][SEQP]
    unsigned short* Ab  = Vtp + (size_t)NH*HD*SEQP;          // [SEQ][DIM]
    unsigned short* xb  = Ab  + (size_t)SEQ*DIM;             // [SEQ][DIM]
    unsigned short* Wqb = xb  + (size_t)SEQ*DIM;             // [DIM][DIM]
    unsigned short* Wkb = Wqb + (size_t)DIM*DIM;
    unsigned short* Wvb = Wkb + (size_t)DIM*DIM;
    unsigned short* Wob = Wvb + (size_t)DIM*DIM;
    float* Pm   = (float*)(Wob + (size_t)DIM*DIM);           // [NH*PMSPLIT][SEQ]
    float* numf = Pm   + (size_t)NH*PMSPLIT*SEQ;             // [4][SEQ][DIM]
    float* denf = numf + (size_t)KSPLIT*SEQ*DIM;             // [4][SEQ][NH]

    const size_t needed_bf16 = ((size_t)SEQ*DIM*4 + (size_t)NH*HD*SEQP
                                + (size_t)DIM*DIM*4) * 2;
    const size_t needed_f32  = ((size_t)NH*PMSPLIT*SEQ + (size_t)KSPLIT*SEQ*DIM
                                + (size_t)KSPLIT*SEQ*NH) * 4;
    const size_t needed_split = needed_bf16 + needed_f32;

    // quake fast inverse sqrt of HEAD_DIM (replicates numpy f32 ops)
    float xx = 64.0f;
    float x2 = xx * 0.5f;
    int ii; memcpy(&ii, &xx, 4);
    ii = 1597463007 - (ii >> 1);
    float y; memcpy(&y, &ii, 4);
    y = y * (1.5f - x2 * y * y);
    const float scaling = y;
    const float k1f = 12102203.17133801f * scaling;   // GIST_A * scaling (f32)

    if(ws_size >= needed_split){
        cvt5_kernel<<<dim3(1536), 256, 0, stream>>>(
            x, Wq, Wk, Wv, Wout, xb, Wqb, Wkb, Wvb, Wob);
        proj_qkv_b_kernel<<<dim3(SEQ/128, DIM/64, 3), 256, 0, stream>>>(
            xb, Wqb, bq, Wkb, bk, Wvb, bv, Qb, Kh, Vtp);
        attn_max_kernel<<<dim3((SEQ/256)*NH*PMSPLIT), 512, 0, stream>>>(Qb, Kh, Pm);
        attn_pv_kernel<<<dim3((SEQ/256)*NH*KSPLIT), 512, 0, stream>>>(
            Qb, Kh, Vtp, Pm, numf, denf, k1f);
        attn_merge_kernel<<<dim3(SEQ*DIM/4/256), 256, 0, stream>>>(numf, denf, Ab);
        proj_out_b_kernel<<<dim3(SEQ/128, DIM/64), 256, 0, stream>>>(Ab, Wob, out);
    } else if(ws_size >= needed_bf16){
        cvt5_kernel<<<dim3(1536), 256, 0, stream>>>(
            x, Wq, Wk, Wv, Wout, xb, Wqb, Wkb, Wvb, Wob);
        proj_qkv_b_kernel<<<dim3(SEQ/128, DIM/64, 3), 256, 0, stream>>>(
            xb, Wqb, bq, Wkb, bk, Wvb, bv, Qb, Kh, Vtp);
        attn_kernel<<<dim3((SEQ/64)*NH), 256, 0, stream>>>(Qb, Kh, Vtp, Ab, k1f);
        proj_out_b_kernel<<<dim3(SEQ/128, DIM/64), 256, 0, stream>>>(Ab, Wob, out);
    } else {
        proj_qkv_kernel<<<dim3(SEQ/128, DIM/64, 3), 256, 0, stream>>>(
            x, Wq, bq, Wk, bk, Wv, bv, Qb, Kh, Vtp);
        attn_kernel<<<dim3((SEQ/64)*NH), 256, 0, stream>>>(Qb, Kh, Vtp, Ab, k1f);
        proj_out_kernel<<<dim3(SEQ/128, DIM/64), 256, 0, stream>>>(Ab, Wout, out);
    }
}